// Round 5
// baseline (1877.125 us; speedup 1.0000x reference)
//
#include <hip/hip_runtime.h>
#include <hip/hip_fp16.h>
#include <math.h>

#define N_MEMBERS 2
#define N_NODES   65536
#define N_EDGES   1048576
#define N_LAYERS  12
#define D         64
#define OFF_STRIDE (N_NODES + 1)
#define NODE_MASK (N_NODES - 1)

// ---------- preprocessing ----------

__global__ __launch_bounds__(256) void count_deg_k(const int* __restrict__ ei,
                                                   int* __restrict__ deg) {
    int e = blockIdx.x * 256 + threadIdx.x;
    int m = blockIdx.y;
    int dst = ei[(size_t)(m * 2 + 1) * N_EDGES + e] & NODE_MASK;
    atomicAdd(&deg[m * N_NODES + dst], 1);
}

__global__ __launch_bounds__(256) void dinv_k(const int* __restrict__ deg,
                                              float* __restrict__ dinv) {
    int i = blockIdx.x * 256 + threadIdx.x;   // over 2*N_NODES
    dinv[i] = 1.0f / sqrtf((float)deg[i] + 1.0f);
}

// ---- parallel 2-level exclusive scan of deg -> off ----
__global__ __launch_bounds__(256) void blocksum_k(const int* __restrict__ deg,
                                                  int* __restrict__ bs) {
    int m = blockIdx.y, blk = blockIdx.x, t = threadIdx.x;
    __shared__ int sh[256];
    sh[t] = deg[m * N_NODES + blk * 256 + t];
    __syncthreads();
    for (int ofs = 128; ofs > 0; ofs >>= 1) {
        if (t < ofs) sh[t] += sh[t + ofs];
        __syncthreads();
    }
    if (t == 0) bs[m * 256 + blk] = sh[0];
}

__global__ __launch_bounds__(256) void scan_bs_k(int* __restrict__ bs) {
    int m = blockIdx.x, t = threadIdx.x;
    __shared__ int sh[256];
    sh[t] = bs[m * 256 + t];
    __syncthreads();
    for (int ofs = 1; ofs < 256; ofs <<= 1) {
        int v = sh[t];
        int a = (t >= ofs) ? sh[t - ofs] : 0;
        __syncthreads();
        sh[t] = v + a;
        __syncthreads();
    }
    bs[m * 256 + t] = (t == 0) ? 0 : sh[t - 1];   // exclusive
}

__global__ __launch_bounds__(256) void scan_off_k(const int* __restrict__ deg,
                                                  const int* __restrict__ bs,
                                                  int* __restrict__ off) {
    int m = blockIdx.y, blk = blockIdx.x, t = threadIdx.x;
    int i = blk * 256 + t;
    int d = deg[m * N_NODES + i];
    __shared__ int sh[256];
    sh[t] = d;
    __syncthreads();
    for (int ofs = 1; ofs < 256; ofs <<= 1) {
        int v = sh[t];
        int a = (t >= ofs) ? sh[t - ofs] : 0;
        __syncthreads();
        sh[t] = v + a;
        __syncthreads();
    }
    off[m * OFF_STRIDE + i] = bs[m * 256 + blk] + sh[t] - d;  // exclusive
    if (i == N_NODES - 1) off[m * OFF_STRIDE + N_NODES] = N_EDGES;
}

// ---- CSR fill: one combined 8B (src, norm) store per edge ----
__global__ __launch_bounds__(256) void fill_k(const int* __restrict__ ei,
                                              const int* __restrict__ off,
                                              int* __restrict__ cursor,
                                              const float* __restrict__ dinv,
                                              int2* __restrict__ csr_es) {
    int e = blockIdx.x * 256 + threadIdx.x;
    int m = blockIdx.y;
    int src = ei[(size_t)(m * 2 + 0) * N_EDGES + e] & NODE_MASK;
    int dst = ei[(size_t)(m * 2 + 1) * N_EDGES + e] & NODE_MASK;
    int pos = off[m * OFF_STRIDE + dst] + atomicAdd(&cursor[m * N_NODES + dst], 1);
    float nrm = dinv[m * N_NODES + src] * dinv[m * N_NODES + dst];
    csr_es[(size_t)m * N_EDGES + pos] = make_int2(src, __float_as_int(nrm));
}

// ---------- per-layer: hw = h @ W[m][layer] (fp16 out) ----------
// lane = output col; W column in 64 VGPRs; h rows read directly from global
// via wave-uniform float4 loads (scalar/broadcast path, no LDS port traffic).
// 4 partial accumulators break the FMA dependence chain.
__global__ __launch_bounds__(256) void gemm_k(const float* __restrict__ h,
                                              const float* __restrict__ Wall,
                                              __half* __restrict__ hw, int layer) {
    int m = blockIdx.y;
    const float* Wg = Wall + (size_t)(m * N_LAYERS + layer) * D * D;
    __shared__ float Wsh[D * D];        // 16 KB, loaded once
    for (int i = threadIdx.x; i < D * D / 4; i += 256)
        ((float4*)Wsh)[i] = ((const float4*)Wg)[i];
    __syncthreads();

    int lane = threadIdx.x & 63;
    int wav  = threadIdx.x >> 6;
    float wreg[D];
    #pragma unroll
    for (int k = 0; k < D; k++) wreg[k] = Wsh[k * D + lane];

    const int NPW = 32;                       // nodes per wave
    int n0 = (blockIdx.x * 4 + wav) * NPW;
    const float* hm = h  + (size_t)m * N_NODES * D;
    __half*      om = hw + (size_t)m * N_NODES * D;
    #pragma unroll 2
    for (int n = n0; n < n0 + NPW; n++) {
        const float4* row = (const float4*)(hm + (size_t)n * D);  // uniform addr
        float a0 = 0.f, a1 = 0.f, a2 = 0.f, a3 = 0.f;
        #pragma unroll
        for (int k4 = 0; k4 < D / 4; k4++) {
            float4 a = row[k4];
            a0 = fmaf(a.x, wreg[4 * k4 + 0], a0);
            a1 = fmaf(a.y, wreg[4 * k4 + 1], a1);
            a2 = fmaf(a.z, wreg[4 * k4 + 2], a2);
            a3 = fmaf(a.w, wreg[4 * k4 + 3], a3);
        }
        om[(size_t)n * D + lane] = __float2half((a0 + a1) + (a2 + a3));
    }
}

// ---------- per-layer aggregate: 4 edges per wave gather instruction ----------
// lane = (sub = lane>>4, fg = lane&15). Each lane gathers ushort4 (4 fp16
// features of feature-group fg) of edge e+sub; accumulates float4. End:
// butterfly reduce over sub (xor 16, 32), lanes 0-15 store float4 (256B/row).
__device__ __forceinline__ float4 cvt4(ushort4 u) {
    union { ushort2 us[2]; __half2 h2[2]; } c;
    c.us[0] = make_ushort2(u.x, u.y);
    c.us[1] = make_ushort2(u.z, u.w);
    float2 a = __half22float2(c.h2[0]);
    float2 b = __half22float2(c.h2[1]);
    return make_float4(a.x, a.y, b.x, b.y);
}

__global__ __launch_bounds__(256) void aggregate_k(const __half* __restrict__ hw,
                                                   float* __restrict__ out,
                                                   const int* __restrict__ off,
                                                   const int2* __restrict__ csr_es,
                                                   const float* __restrict__ dinv,
                                                   const float* __restrict__ ball,
                                                   int layer, int relu) {
    int m = blockIdx.y;
    int n = blockIdx.x * 4 + (threadIdx.x >> 6);
    int lane = threadIdx.x & 63;
    int fg   = lane & 15;
    int sub  = lane >> 4;
    const ushort4* hm4 = (const ushort4*)(hw + (size_t)m * N_NODES * D);
    const int*     ob  = off + m * OFF_STRIDE;
    const int2*    eb  = csr_es + (size_t)m * N_EDGES;

    float4 acc = make_float4(0.f, 0.f, 0.f, 0.f);
    int e0 = ob[n], e1 = ob[n + 1];
    #pragma unroll 2
    for (int e = e0; e < e1; e += 4) {
        int ee  = e + sub;
        int idx = (ee < e1) ? ee : (e1 - 1);
        int2 p  = eb[idx];
        float w = (ee < e1) ? __int_as_float(p.y) : 0.0f;
        float4 g = cvt4(hm4[(size_t)p.x * 16 + fg]);
        acc.x = fmaf(w, g.x, acc.x);
        acc.y = fmaf(w, g.y, acc.y);
        acc.z = fmaf(w, g.z, acc.z);
        acc.w = fmaf(w, g.w, acc.w);
    }
    // reduce over sub (lanes with equal fg): xor 16, 32
    #pragma unroll
    for (int msk = 16; msk < 64; msk <<= 1) {
        acc.x += __shfl_xor(acc.x, msk);
        acc.y += __shfl_xor(acc.y, msk);
        acc.z += __shfl_xor(acc.z, msk);
        acc.w += __shfl_xor(acc.w, msk);
    }

    // self-loop + bias + relu (all lanes compute; lanes 0-15 store)
    float dv  = dinv[m * N_NODES + n];
    float dv2 = dv * dv;
    float4 s  = cvt4(hm4[(size_t)n * 16 + fg]);
    float4 bi = ((const float4*)(ball + (size_t)(m * N_LAYERS + layer) * D))[fg];
    acc.x = fmaf(dv2, s.x, acc.x) + bi.x;
    acc.y = fmaf(dv2, s.y, acc.y) + bi.y;
    acc.z = fmaf(dv2, s.z, acc.z) + bi.z;
    acc.w = fmaf(dv2, s.w, acc.w) + bi.w;
    if (relu) {
        acc.x = fmaxf(acc.x, 0.f);
        acc.y = fmaxf(acc.y, 0.f);
        acc.z = fmaxf(acc.z, 0.f);
        acc.w = fmaxf(acc.w, 0.f);
    }
    if (lane < 16)
        ((float4*)(out + (size_t)m * N_NODES * D + (size_t)n * D))[lane] = acc;
}

// ---------- host ----------

extern "C" void kernel_launch(void* const* d_in, const int* in_sizes, int n_in,
                              void* d_out, int out_size, void* d_ws, size_t ws_size,
                              hipStream_t stream) {
    (void)in_sizes; (void)n_in; (void)out_size; (void)ws_size;
    const float* x  = (const float*)d_in[0];
    const int*   ei = (const int*)d_in[1];
    const float* W  = (const float*)d_in[2];
    const float* b  = (const float*)d_in[3];
    float* out = (float*)d_out;

    char* ws = (char*)d_ws;
    size_t o = 0;
    auto take = [&](size_t bytes) -> void* {
        void* p = ws + o;
        o = (o + bytes + 255) & ~(size_t)255;
        return p;
    };
    int*    deg      = (int*)   take((size_t)N_MEMBERS * N_NODES * 4);
    int*    cursor   = (int*)   take((size_t)N_MEMBERS * N_NODES * 4);
    float*  dinv     = (float*) take((size_t)N_MEMBERS * N_NODES * 4);
    int*    off      = (int*)   take((size_t)N_MEMBERS * OFF_STRIDE * 4);
    int*    bs       = (int*)   take((size_t)N_MEMBERS * 256 * 4);
    int2*   csr_es   = (int2*)  take((size_t)N_MEMBERS * N_EDGES * 8);
    __half* tbuf     = (__half*)take((size_t)N_MEMBERS * N_NODES * D * 2);
    float*  hbuf     = (float*) take((size_t)N_MEMBERS * N_NODES * D * 4);

    // zero deg + cursor (adjacent, both 256-padded)
    hipMemsetAsync(deg, 0, 2 * (size_t)N_MEMBERS * N_NODES * 4, stream);

    count_deg_k<<<dim3(N_EDGES / 256, N_MEMBERS), 256, 0, stream>>>(ei, deg);
    dinv_k<<<dim3((N_MEMBERS * N_NODES) / 256), 256, 0, stream>>>(deg, dinv);
    blocksum_k<<<dim3(N_NODES / 256, N_MEMBERS), 256, 0, stream>>>(deg, bs);
    scan_bs_k<<<dim3(N_MEMBERS), 256, 0, stream>>>(bs);
    scan_off_k<<<dim3(N_NODES / 256, N_MEMBERS), 256, 0, stream>>>(deg, bs, off);
    fill_k<<<dim3(N_EDGES / 256, N_MEMBERS), 256, 0, stream>>>(ei, off, cursor, dinv, csr_es);

    const float* hin = x;
    for (int j = 0; j < N_LAYERS; j++) {
        gemm_k<<<dim3(N_NODES / 128, N_MEMBERS), 256, 0, stream>>>(hin, W, tbuf, j);
        float* dst = (j == N_LAYERS - 1) ? out : hbuf;
        aggregate_k<<<dim3(N_NODES / 4, N_MEMBERS), 256, 0, stream>>>(
            tbuf, dst, off, csr_es, dinv, b, j, (j < N_LAYERS - 1) ? 1 : 0);
        hin = hbuf;
    }
}

// Round 6
// 1236.484 us; speedup vs baseline: 1.5181x; 1.5181x over previous
//
#include <hip/hip_runtime.h>
#include <hip/hip_fp16.h>
#include <math.h>

#define N_MEMBERS 2
#define N_NODES   65536
#define N_EDGES   1048576
#define N_LAYERS  12
#define D         64
#define OFF_STRIDE (N_NODES + 1)
#define NODE_MASK (N_NODES - 1)

typedef _Float16 f16;
typedef f16   f16x8 __attribute__((ext_vector_type(8)));
typedef float f32x4 __attribute__((ext_vector_type(4)));

// ---------- preprocessing ----------

__global__ __launch_bounds__(256) void count_deg_k(const int* __restrict__ ei,
                                                   int* __restrict__ deg) {
    int e = blockIdx.x * 256 + threadIdx.x;
    int m = blockIdx.y;
    int dst = ei[(size_t)(m * 2 + 1) * N_EDGES + e] & NODE_MASK;
    atomicAdd(&deg[m * N_NODES + dst], 1);
}

__global__ __launch_bounds__(256) void dinv_k(const int* __restrict__ deg,
                                              float* __restrict__ dinv) {
    int i = blockIdx.x * 256 + threadIdx.x;   // over 2*N_NODES
    dinv[i] = 1.0f / sqrtf((float)deg[i] + 1.0f);
}

// ---- parallel 2-level exclusive scan of deg -> off ----
__global__ __launch_bounds__(256) void blocksum_k(const int* __restrict__ deg,
                                                  int* __restrict__ bs) {
    int m = blockIdx.y, blk = blockIdx.x, t = threadIdx.x;
    __shared__ int sh[256];
    sh[t] = deg[m * N_NODES + blk * 256 + t];
    __syncthreads();
    for (int ofs = 128; ofs > 0; ofs >>= 1) {
        if (t < ofs) sh[t] += sh[t + ofs];
        __syncthreads();
    }
    if (t == 0) bs[m * 256 + blk] = sh[0];
}

__global__ __launch_bounds__(256) void scan_bs_k(int* __restrict__ bs) {
    int m = blockIdx.x, t = threadIdx.x;
    __shared__ int sh[256];
    sh[t] = bs[m * 256 + t];
    __syncthreads();
    for (int ofs = 1; ofs < 256; ofs <<= 1) {
        int v = sh[t];
        int a = (t >= ofs) ? sh[t - ofs] : 0;
        __syncthreads();
        sh[t] = v + a;
        __syncthreads();
    }
    bs[m * 256 + t] = (t == 0) ? 0 : sh[t - 1];   // exclusive
}

__global__ __launch_bounds__(256) void scan_off_k(const int* __restrict__ deg,
                                                  const int* __restrict__ bs,
                                                  int* __restrict__ off) {
    int m = blockIdx.y, blk = blockIdx.x, t = threadIdx.x;
    int i = blk * 256 + t;
    int d = deg[m * N_NODES + i];
    __shared__ int sh[256];
    sh[t] = d;
    __syncthreads();
    for (int ofs = 1; ofs < 256; ofs <<= 1) {
        int v = sh[t];
        int a = (t >= ofs) ? sh[t - ofs] : 0;
        __syncthreads();
        sh[t] = v + a;
        __syncthreads();
    }
    off[m * OFF_STRIDE + i] = bs[m * 256 + blk] + sh[t] - d;  // exclusive
    if (i == N_NODES - 1) off[m * OFF_STRIDE + N_NODES] = N_EDGES;
}

// ---- CSR fill: one combined 8B (src, norm) store per edge ----
__global__ __launch_bounds__(256) void fill_k(const int* __restrict__ ei,
                                              const int* __restrict__ off,
                                              int* __restrict__ cursor,
                                              const float* __restrict__ dinv,
                                              int2* __restrict__ csr_es) {
    int e = blockIdx.x * 256 + threadIdx.x;
    int m = blockIdx.y;
    int src = ei[(size_t)(m * 2 + 0) * N_EDGES + e] & NODE_MASK;
    int dst = ei[(size_t)(m * 2 + 1) * N_EDGES + e] & NODE_MASK;
    int pos = off[m * OFF_STRIDE + dst] + atomicAdd(&cursor[m * N_NODES + dst], 1);
    float nrm = dinv[m * N_NODES + src] * dinv[m * N_NODES + dst];
    csr_es[(size_t)m * N_EDGES + pos] = make_int2(src, __float_as_int(nrm));
}

// ---------- per-layer GEMM via MFMA, split-fp16 for fp32-class accuracy -----
// hw[n][c] = sum_k h[n][k] * W[k][c], computed as (Ahi+Alo)(Bhi+Blo) with the
// AlBl term dropped (~2^-22 rel). A-frag: m=lane&15, k=quad*8+j (K=32/step).
// B-frag: n=lane&15, same k. C/D: col=lane&15, row=quad*4+reg.
__device__ __forceinline__ void split8(const float* p, f16x8& hi, f16x8& lo) {
    float4 a = *(const float4*)p;
    float4 b = *(const float4*)(p + 4);
    float v[8] = {a.x, a.y, a.z, a.w, b.x, b.y, b.z, b.w};
    #pragma unroll
    for (int i = 0; i < 8; i++) {
        f16 h = (f16)v[i];
        hi[i] = h;
        lo[i] = (f16)(v[i] - (float)h);
    }
}

__global__ __launch_bounds__(256) void gemm_mfma_k(const float* __restrict__ h,
                                                   const float* __restrict__ Wall,
                                                   __half* __restrict__ hw, int layer) {
    int m = blockIdx.y;
    const float* Wg = Wall + (size_t)(m * N_LAYERS + layer) * D * D;
    // W transposed + hi/lo split into LDS: W*[c][k], stride 72 halves (pad)
    __shared__ __align__(16) _Float16 Whi[D][72];
    __shared__ __align__(16) _Float16 Wlo[D][72];
    for (int idx = threadIdx.x; idx < D * D / 4; idx += 256) {
        float4 v = ((const float4*)Wg)[idx];
        int k  = idx >> 4;           // row of W
        int c0 = (idx & 15) << 2;    // col of W
        float vv[4] = {v.x, v.y, v.z, v.w};
        #pragma unroll
        for (int i = 0; i < 4; i++) {
            f16 hi = (f16)vv[i];
            Whi[c0 + i][k] = hi;
            Wlo[c0 + i][k] = (f16)(vv[i] - (float)hi);
        }
    }
    __syncthreads();

    int lane = threadIdx.x & 63;
    int wav  = threadIdx.x >> 6;
    int nn   = lane & 15;
    int quad = lane >> 4;

    // B fragments (held for whole kernel): [t*2+s]
    f16x8 Bh[8], Bl[8];
    #pragma unroll
    for (int t = 0; t < 4; t++)
        #pragma unroll
        for (int s = 0; s < 2; s++) {
            Bh[t * 2 + s] = *(const f16x8*)&Whi[t * 16 + nn][s * 32 + quad * 8];
            Bl[t * 2 + s] = *(const f16x8*)&Wlo[t * 16 + nn][s * 32 + quad * 8];
        }

    const float* hm = h  + (size_t)m * N_NODES * D;
    __half*      om = hw + (size_t)m * N_NODES * D;
    int base = blockIdx.x * 256 + wav * 64;
    for (int g = 0; g < 4; g++) {
        int n0 = base + g * 16;
        const float* hrow = hm + (size_t)(n0 + nn) * D;
        f16x8 ah[2], al[2];
        split8(hrow + quad * 8,      ah[0], al[0]);   // k = 0..31
        split8(hrow + 32 + quad * 8, ah[1], al[1]);   // k = 32..63
        #pragma unroll
        for (int t = 0; t < 4; t++) {
            f32x4 c = {0.f, 0.f, 0.f, 0.f};
            #pragma unroll
            for (int s = 0; s < 2; s++) {
                c = __builtin_amdgcn_mfma_f32_16x16x32_f16(ah[s], Bh[t*2+s], c, 0, 0, 0);
                c = __builtin_amdgcn_mfma_f32_16x16x32_f16(al[s], Bh[t*2+s], c, 0, 0, 0);
                c = __builtin_amdgcn_mfma_f32_16x16x32_f16(ah[s], Bl[t*2+s], c, 0, 0, 0);
            }
            #pragma unroll
            for (int r = 0; r < 4; r++)
                om[(size_t)(n0 + quad * 4 + r) * D + t * 16 + nn] = __float2half((float)c[r]);
        }
    }
}

// ---------- per-layer aggregate: 4 edges per wave gather instruction ----------
__device__ __forceinline__ float4 cvt4(ushort4 u) {
    union { ushort2 us[2]; __half2 h2[2]; } c;
    c.us[0] = make_ushort2(u.x, u.y);
    c.us[1] = make_ushort2(u.z, u.w);
    float2 a = __half22float2(c.h2[0]);
    float2 b = __half22float2(c.h2[1]);
    return make_float4(a.x, a.y, b.x, b.y);
}

__global__ __launch_bounds__(256) void aggregate_k(const __half* __restrict__ hw,
                                                   float* __restrict__ out,
                                                   const int* __restrict__ off,
                                                   const int2* __restrict__ csr_es,
                                                   const float* __restrict__ dinv,
                                                   const float* __restrict__ ball,
                                                   int layer, int relu) {
    int m = blockIdx.y;
    int n = blockIdx.x * 4 + (threadIdx.x >> 6);
    int lane = threadIdx.x & 63;
    int fg   = lane & 15;
    int sub  = lane >> 4;
    const ushort4* hm4 = (const ushort4*)(hw + (size_t)m * N_NODES * D);
    const int*     ob  = off + m * OFF_STRIDE;
    const int2*    eb  = csr_es + (size_t)m * N_EDGES;

    float4 acc = make_float4(0.f, 0.f, 0.f, 0.f);
    int e0 = ob[n], e1 = ob[n + 1];
    #pragma unroll 2
    for (int e = e0; e < e1; e += 4) {
        int ee  = e + sub;
        int idx = (ee < e1) ? ee : (e1 - 1);
        int2 p  = eb[idx];
        float w = (ee < e1) ? __int_as_float(p.y) : 0.0f;
        float4 g = cvt4(hm4[(size_t)p.x * 16 + fg]);
        acc.x = fmaf(w, g.x, acc.x);
        acc.y = fmaf(w, g.y, acc.y);
        acc.z = fmaf(w, g.z, acc.z);
        acc.w = fmaf(w, g.w, acc.w);
    }
    #pragma unroll
    for (int msk = 16; msk < 64; msk <<= 1) {
        acc.x += __shfl_xor(acc.x, msk);
        acc.y += __shfl_xor(acc.y, msk);
        acc.z += __shfl_xor(acc.z, msk);
        acc.w += __shfl_xor(acc.w, msk);
    }

    float dv  = dinv[m * N_NODES + n];
    float dv2 = dv * dv;
    float4 s  = cvt4(hm4[(size_t)n * 16 + fg]);
    float4 bi = ((const float4*)(ball + (size_t)(m * N_LAYERS + layer) * D))[fg];
    acc.x = fmaf(dv2, s.x, acc.x) + bi.x;
    acc.y = fmaf(dv2, s.y, acc.y) + bi.y;
    acc.z = fmaf(dv2, s.z, acc.z) + bi.z;
    acc.w = fmaf(dv2, s.w, acc.w) + bi.w;
    if (relu) {
        acc.x = fmaxf(acc.x, 0.f);
        acc.y = fmaxf(acc.y, 0.f);
        acc.z = fmaxf(acc.z, 0.f);
        acc.w = fmaxf(acc.w, 0.f);
    }
    if (lane < 16)
        ((float4*)(out + (size_t)m * N_NODES * D + (size_t)n * D))[lane] = acc;
}

// ---------- host ----------

extern "C" void kernel_launch(void* const* d_in, const int* in_sizes, int n_in,
                              void* d_out, int out_size, void* d_ws, size_t ws_size,
                              hipStream_t stream) {
    (void)in_sizes; (void)n_in; (void)out_size; (void)ws_size;
    const float* x  = (const float*)d_in[0];
    const int*   ei = (const int*)d_in[1];
    const float* W  = (const float*)d_in[2];
    const float* b  = (const float*)d_in[3];
    float* out = (float*)d_out;

    char* ws = (char*)d_ws;
    size_t o = 0;
    auto take = [&](size_t bytes) -> void* {
        void* p = ws + o;
        o = (o + bytes + 255) & ~(size_t)255;
        return p;
    };
    int*    deg      = (int*)   take((size_t)N_MEMBERS * N_NODES * 4);
    int*    cursor   = (int*)   take((size_t)N_MEMBERS * N_NODES * 4);
    float*  dinv     = (float*) take((size_t)N_MEMBERS * N_NODES * 4);
    int*    off      = (int*)   take((size_t)N_MEMBERS * OFF_STRIDE * 4);
    int*    bs       = (int*)   take((size_t)N_MEMBERS * 256 * 4);
    int2*   csr_es   = (int2*)  take((size_t)N_MEMBERS * N_EDGES * 8);
    __half* tbuf     = (__half*)take((size_t)N_MEMBERS * N_NODES * D * 2);
    float*  hbuf     = (float*) take((size_t)N_MEMBERS * N_NODES * D * 4);

    // zero deg + cursor (adjacent, both 256-padded)
    hipMemsetAsync(deg, 0, 2 * (size_t)N_MEMBERS * N_NODES * 4, stream);

    count_deg_k<<<dim3(N_EDGES / 256, N_MEMBERS), 256, 0, stream>>>(ei, deg);
    dinv_k<<<dim3((N_MEMBERS * N_NODES) / 256), 256, 0, stream>>>(deg, dinv);
    blocksum_k<<<dim3(N_NODES / 256, N_MEMBERS), 256, 0, stream>>>(deg, bs);
    scan_bs_k<<<dim3(N_MEMBERS), 256, 0, stream>>>(bs);
    scan_off_k<<<dim3(N_NODES / 256, N_MEMBERS), 256, 0, stream>>>(deg, bs, off);
    fill_k<<<dim3(N_EDGES / 256, N_MEMBERS), 256, 0, stream>>>(ei, off, cursor, dinv, csr_es);

    const float* hin = x;
    for (int j = 0; j < N_LAYERS; j++) {
        gemm_mfma_k<<<dim3(N_NODES / 256, N_MEMBERS), 256, 0, stream>>>(hin, W, tbuf, j);
        float* dst = (j == N_LAYERS - 1) ? out : hbuf;
        aggregate_k<<<dim3(N_NODES / 4, N_MEMBERS), 256, 0, stream>>>(
            tbuf, dst, off, csr_es, dinv, b, j, (j < N_LAYERS - 1) ? 1 : 0);
        hin = hbuf;
    }
}